// Round 2
// baseline (1477.664 us; speedup 1.0000x reference)
//
#include <hip/hip_runtime.h>
#include <math.h>

#define BDIM 4096
#define DDIM 256
#define NSTATE 9000000L
#define PREFIX 3674116L          // floats of o bank-0 prefix used as scratch in fb mode

#define NTILES 1024
#define CHUNK_F 16384L           // floats per state-copy chunk (64 KB)
#define CPB 550                  // chunks per bank = ceil(9e6/16384)
#define NCHUNKS (8*CPB)          // 4400
#define NPFX 225                 // prefix chunks = ceil(PREFIX/CHUNK_F)
#define GRID 768                 // 256 CU x 3 blocks; co-residency NOT required

#define C_ALPHA 0.5f
#define C_GAMMA_S 0.8f
#define C_GAMMA_U 0.9f
#define C_RHO 6.0f
#define C_EPS 1e-14f
#define C_ETA 0.01f
#define C_TAU_MIN 0.001f
#define C_TAU_MAX 1.0f
#define C_GRAD_CLIP 5.0f

typedef unsigned short u16;
typedef __attribute__((ext_vector_type(8))) short short8;
typedef __attribute__((ext_vector_type(16))) float f32x16;
typedef __attribute__((ext_vector_type(4))) float nf4;

#define MFMA32 __builtin_amdgcn_mfma_f32_32x32x16_bf16
#define AGS __HIP_MEMORY_SCOPE_AGENT

__device__ inline u16 f2bf(float f) {
    unsigned u = __float_as_uint(f);
    unsigned r = (u + 0x7FFFu + ((u >> 16) & 1u)) >> 16;
    return (u16)r;
}
__device__ inline float bf2f(u16 h) { return __uint_as_float(((unsigned)h) << 16); }

__device__ inline void nt_copy4(const nf4* __restrict__ s, long k, float* __restrict__ dbase) {
    nf4 v = __builtin_nontemporal_load(&s[k]);
    float* dp = dbase + 4 * k;
    __builtin_nontemporal_store(v.x, dp + 0);
    __builtin_nontemporal_store(v.y, dp + 1);
    __builtin_nontemporal_store(v.z, dp + 2);
    __builtin_nontemporal_store(v.w, dp + 3);
}

// softmax partial macros (reference block-locals of the GEMM tile scope)
#define COLPART(A0, A1, CT) do {                                                   \
        int gc = colbase + (CT) * 32 + lc;                                         \
        float itc = colIT[gc];                                                     \
        float m = -INFINITY;                                                       \
        _Pragma("unroll") for (int e = 0; e < 16; ++e) {                           \
            m = fmaxf(m, (A0)[e]); m = fmaxf(m, (A1)[e]); }                        \
        m = fmaxf(m, __shfl_xor(m, 32));                                           \
        float S1 = 0.f, S2 = 0.f;                                                  \
        _Pragma("unroll") for (int e = 0; e < 16; ++e) {                           \
            float v0 = (A0)[e]; float e0 = __expf((v0 - m) * itc); S1 += e0; S2 += e0 * v0; \
            float v1 = (A1)[e]; float e1 = __expf((v1 - m) * itc); S1 += e1; S2 += e1 * v1; } \
        S1 += __shfl_xor(S1, 32); S2 += __shfl_xor(S2, 32);                        \
        if (h == 0) { int slot = by * 2 + rw;                                      \
            cPM [slot * 4096 + gc] = m;                                            \
            cPS1[slot * 4096 + gc] = S1;                                           \
            cPS2[slot * 4096 + gc] = S2; }                                         \
    } while (0)

#define ROWPART(TB) do {                                                           \
        float* Tb = (TB);                                                          \
        _Pragma("unroll") for (int q = 0; q < 4; ++q) {                            \
            _Pragma("unroll") for (int j = 0; j < 4; ++j) {                        \
                int rr = 8 * q + 4 * h + j;                                        \
                Tb[(rr     ) * 68 + lc     ] = acc00[4 * q + j];                   \
                Tb[(rr     ) * 68 + lc + 32] = acc01[4 * q + j];                   \
                Tb[(rr + 32) * 68 + lc     ] = acc10[4 * q + j];                   \
                Tb[(rr + 32) * 68 + lc + 32] = acc11[4 * q + j]; } }               \
        float itr = rowIT[rowbase + l];                                            \
        float4 vv[16];                                                             \
        _Pragma("unroll") for (int c = 0; c < 16; ++c)                             \
            vv[c] = *(const float4*)&Tb[l * 68 + 4 * c];                           \
        float m = -INFINITY;                                                       \
        _Pragma("unroll") for (int c = 0; c < 16; ++c)                             \
            m = fmaxf(m, fmaxf(fmaxf(vv[c].x, vv[c].y), fmaxf(vv[c].z, vv[c].w))); \
        float S1 = 0.f, S2 = 0.f;                                                  \
        _Pragma("unroll") for (int c = 0; c < 16; ++c) {                           \
            float e0 = __expf((vv[c].x - m) * itr); S1 += e0; S2 += e0 * vv[c].x;  \
            float e1 = __expf((vv[c].y - m) * itr); S1 += e1; S2 += e1 * vv[c].y;  \
            float e2 = __expf((vv[c].z - m) * itr); S1 += e2; S2 += e2 * vv[c].z;  \
            float e3 = __expf((vv[c].w - m) * itr); S1 += e3; S2 += e3 * vv[c].w; }\
        int slot = bx * 2 + cw;                                                    \
        rPM [slot * 4096 + rowbase + l] = m;                                       \
        rPS1[slot * 4096 + rowbase + l] = S1;                                      \
        rPS2[slot * 4096 + rowbase + l] = S2;                                      \
        if (bx == by && rw == cw) diag[rowbase + l] = Tb[l * 68 + l];              \
    } while (0)

// counter init (runs before kall each iteration; ws is poisoned by the harness)
__global__ void kinit(float* ws) {
    int t = threadIdx.x;
    if (t < 12) ((int*)(ws + 8196))[t] = 0;   // ticket + 11 work/done counters
    if (t == 12) ws[8192] = 0.f;              // loss_I accumulator
    if (t == 13) ws[8193] = 0.f;              // loss_T accumulator
}

// ---------------- single persistent kernel, deadlock-free by construction ----------------
// All cross-block deps are ITEM-completion counters (release add / acquire spin).
// A spinning block only waits on items already grabbed by running (resident) blocks;
// late blocks find all queues drained and fall through. Any grid size is safe.
__global__ __launch_bounds__(256, 3) void kall(
    const float* __restrict__ zis, const float* __restrict__ zjs,
    const int* __restrict__ ids,
    const float* __restrict__ s_I, const float* __restrict__ s_T,
    const float* __restrict__ b_I, const float* __restrict__ b_T,
    const float* __restrict__ u_I, const float* __restrict__ u_T,
    const float* __restrict__ tau_I, const float* __restrict__ tau_T,
    float* O, float* ws, float* Sb, int fb)
{
    __shared__ union {
        float T[2][64 * 68];
        struct { float ssq[32]; float red[512]; } p0;
    } sm;
    __shared__ int sgrab, skind;

    const int bid = blockIdx.x;
    const int t = threadIdx.x;

    float* o = O + 16387;
    float* rowIT = ws;
    float* colIT = ws + 4096;
    float* acc4  = ws + 8192;
    float* sc_arrs = ws + 16384;           // 8 x 4096 staged scatter values
    int* ip = (int*)(ws + 8196);
    int* ticket   = ip + 0;
    int* p0_ctr   = ip + 1;  int* p0done  = ip + 2;
    int* tile_ctr = ip + 3;  int* p1done  = ip + 4;
    int* copy_ctr = ip + 5;  int* c_done  = ip + 6;
    int* m_ctr    = ip + 7;  int* m_done  = ip + 8;
    int* pfx_ctr  = ip + 9;  int* pfx_done= ip + 10;
    int* sc_ctr   = ip + 11;

    float* rPM  = Sb;            float* rPS1 = Sb + 262144;  float* rPS2 = Sb + 524288;
    float* cPM  = Sb + 786432;   float* cPS1 = Sb + 1048576; float* cPS2 = Sb + 1310720;
    float* diag = Sb + 1572864;
    u16* ABw = (u16*)(Sb + 1576960);
    const u16* Ah = (const u16*)ABw;
    const u16* Al = Ah + 1048576;
    const u16* Bh = Al + 1048576;
    const u16* Bl = Bh + 1048576;

#define WAITGE(P, TGT) do { if (t == 0) {                                              \
        while (__hip_atomic_load((P), __ATOMIC_ACQUIRE, AGS) < (TGT))                  \
            __builtin_amdgcn_s_sleep(8);                                               \
        __threadfence(); }                                                             \
        __syncthreads(); } while (0)

#define DONE1(P) do { __syncthreads(); if (t == 0) {                                   \
        __threadfence();                                                               \
        __hip_atomic_fetch_add((P), 1, __ATOMIC_RELEASE, AGS); } } while (0)

    // dense copy of one state chunk, float4 loads + scalar NT stores (o is 4B-aligned only)
    auto copy_chunk = [&](int c) {
        int bank = c / CPB;
        long f0 = (long)(c - bank * CPB) * CHUNK_F;
        long fend = f0 + CHUNK_F; if (fend > NSTATE) fend = NSTATE;
        if (bank == 0 && fb) {
            if (fend <= PREFIX) return;        // prefix handled after merge
            if (f0 < PREFIX) f0 = PREFIX;      // PREFIX is 16B-aligned in floats
        }
        const float* src;
        switch (bank) {
            case 0: src = s_I; break;  case 1: src = s_T; break;
            case 2: src = b_I; break;  case 3: src = b_T; break;
            case 4: src = u_I; break;  case 5: src = u_T; break;
            case 6: src = tau_I; break; default: src = tau_T; break;
        }
        float* dst = o + (long)bank * NSTATE;
        const nf4* s4 = (const nf4*)src;
        for (long k = f0 / 4 + t; k < fend / 4; k += 256) nt_copy4(s4, k, dst);
    };

    // ---------------- P0: prep items (0..255 fragments, 256 = tau/IT) ----------------
    for (;;) {
        __syncthreads();
        if (t == 0) sgrab = atomicAdd(p0_ctr, 1);
        __syncthreads();
        int it0 = sgrab;
        if (it0 >= 257) break;

        if (it0 == 256) {
            float sI = 0.f, sT = 0.f;
            for (int i = t; i < BDIM; i += 256) {
                int id = ids[i];
                float ti = tau_I[id], tt = tau_T[id];
                rowIT[i] = 1.0f / ti;
                colIT[i] = 1.0f / tt;
                sI += ti; sT += tt;
            }
            sm.p0.red[t] = sI; sm.p0.red[256 + t] = sT;
            __syncthreads();
            for (int s = 128; s > 0; s >>= 1) {
                if (t < s) { sm.p0.red[t] += sm.p0.red[t + s]; sm.p0.red[256 + t] += sm.p0.red[256 + t + s]; }
                __syncthreads();
            }
            if (t == 0) { acc4[2] = sm.p0.red[0]; acc4[3] = sm.p0.red[256]; }
        } else {
            bool isB = it0 >= 128;
            const float* Z = isB ? zjs : zis;
            u16* H = isB ? (ABw + 2097152) : ABw;
            u16* L = isB ? (ABw + 3145728) : (ABw + 1048576);
            int rblk = it0 & 127;
            int r = t & 31, kc0 = t >> 5;
            int row = rblk * 32 + r;

            if (t < 32) sm.p0.ssq[t] = 0.f;
            __syncthreads();

            float4 v[8];
            float partial = 0.f;
#pragma unroll
            for (int c = 0; c < 4; ++c) {
                int kc = kc0 + 8 * c;
                float4 a = *(const float4*)&Z[(size_t)row * DDIM + kc * 8];
                float4 b = *(const float4*)&Z[(size_t)row * DDIM + kc * 8 + 4];
                v[2 * c] = a; v[2 * c + 1] = b;
                partial += a.x * a.x + a.y * a.y + a.z * a.z + a.w * a.w;
                partial += b.x * b.x + b.y * b.y + b.z * b.z + b.w * b.w;
            }
            atomicAdd(&sm.p0.ssq[r], partial);
            __syncthreads();
            float inv = rsqrtf(sm.p0.ssq[r]);

#pragma unroll
            for (int c = 0; c < 4; ++c) {
                int kc = kc0 + 8 * c;
                float f[8];
                f[0] = v[2*c].x * inv;   f[1] = v[2*c].y * inv;
                f[2] = v[2*c].z * inv;   f[3] = v[2*c].w * inv;
                f[4] = v[2*c+1].x * inv; f[5] = v[2*c+1].y * inv;
                f[6] = v[2*c+1].z * inv; f[7] = v[2*c+1].w * inv;
                u16 hh[8], ll[8];
#pragma unroll
                for (int j = 0; j < 8; ++j) {
                    hh[j] = f2bf(f[j]);
                    ll[j] = f2bf(f[j] - bf2f(hh[j]));
                }
                size_t base = (size_t)rblk * 8192 + (size_t)kc * 256 + (size_t)r * 8;
                uint4 ph, pl;
                ph.x = (unsigned)hh[0] | ((unsigned)hh[1] << 16);
                ph.y = (unsigned)hh[2] | ((unsigned)hh[3] << 16);
                ph.z = (unsigned)hh[4] | ((unsigned)hh[5] << 16);
                ph.w = (unsigned)hh[6] | ((unsigned)hh[7] << 16);
                pl.x = (unsigned)ll[0] | ((unsigned)ll[1] << 16);
                pl.y = (unsigned)ll[2] | ((unsigned)ll[3] << 16);
                pl.z = (unsigned)ll[4] | ((unsigned)ll[5] << 16);
                pl.w = (unsigned)ll[6] | ((unsigned)ll[7] << 16);
                *(uint4*)(H + base) = ph;
                *(uint4*)(L + base) = pl;
            }
        }
        DONE1(p0done);
    }

    // ---------------- Phase B: GEMM tiles (gated on p0done) interleaved with copy ----------------
    const bool mergeprio = (bid < 32);   // these blocks skip copy-drain to start merge early
    for (;;) {
        __syncthreads();
        if (t == 0) {
            int kind, item = -1;
            if (__hip_atomic_load(p0done, __ATOMIC_ACQUIRE, AGS) >= 257) {
                item = atomicAdd(tile_ctr, 1);
                if (item < NTILES) kind = 1;
                else if (mergeprio) kind = 0;
                else { item = atomicAdd(copy_ctr, 1); kind = (item < NCHUNKS) ? 2 : 0; }
            } else {
                item = atomicAdd(copy_ctr, 1);
                kind = (item < NCHUNKS) ? 2 : 3;
            }
            sgrab = item; skind = kind;
        }
        __syncthreads();
        int kind = skind, item = sgrab;
        if (kind == 0) break;
        if (kind == 1) {
            int gid = item;
            int by = gid >> 5, bx = gid & 31;
            int w = t >> 6, l = t & 63;
            int rw = w & 1, cw = w >> 1;
            int h = l >> 5, lc = l & 31;
            int rowbase = by * 128 + rw * 64;
            int colbase = bx * 128 + cw * 64;

            const u16* pAh = Ah + (size_t)(by * 4 + rw * 2) * 8192;
            const u16* pAl = Al + (size_t)(by * 4 + rw * 2) * 8192;
            const u16* pBh = Bh + (size_t)(bx * 4 + cw * 2) * 8192;
            const u16* pBl = Bl + (size_t)(bx * 4 + cw * 2) * 8192;

            f32x16 acc00, acc01, acc10, acc11;
#pragma unroll
            for (int e = 0; e < 16; ++e) { acc00[e] = 0.f; acc01[e] = 0.f; acc10[e] = 0.f; acc11[e] = 0.f; }

            for (int s = 0; s < 16; ++s) {
                int off = s * 512 + l * 8;
                short8 a0h = *(const short8*)(pAh + off);
                short8 a1h = *(const short8*)(pAh + 8192 + off);
                short8 a0l = *(const short8*)(pAl + off);
                short8 a1l = *(const short8*)(pAl + 8192 + off);
                short8 b0h = *(const short8*)(pBh + off);
                short8 b1h = *(const short8*)(pBh + 8192 + off);
                short8 b0l = *(const short8*)(pBl + off);
                short8 b1l = *(const short8*)(pBl + 8192 + off);

                acc00 = MFMA32(a0h, b0h, acc00, 0, 0, 0);
                acc01 = MFMA32(a0h, b1h, acc01, 0, 0, 0);
                acc10 = MFMA32(a1h, b0h, acc10, 0, 0, 0);
                acc11 = MFMA32(a1h, b1h, acc11, 0, 0, 0);
                acc00 = MFMA32(a0h, b0l, acc00, 0, 0, 0);
                acc01 = MFMA32(a0h, b1l, acc01, 0, 0, 0);
                acc10 = MFMA32(a1h, b0l, acc10, 0, 0, 0);
                acc11 = MFMA32(a1h, b1l, acc11, 0, 0, 0);
                acc00 = MFMA32(a0l, b0h, acc00, 0, 0, 0);
                acc01 = MFMA32(a0l, b1h, acc01, 0, 0, 0);
                acc10 = MFMA32(a1l, b0h, acc10, 0, 0, 0);
                acc11 = MFMA32(a1l, b1h, acc11, 0, 0, 0);
            }

            COLPART(acc00, acc10, 0);
            COLPART(acc01, acc11, 1);

            if (w < 2) ROWPART(sm.T[w]);
            __syncthreads();
            if (w >= 2) ROWPART(sm.T[w - 2]);

            DONE1(p1done);
        } else if (kind == 2) {
            copy_chunk(item);
            DONE1(c_done);
        } else { // kind 3: copy drained but GEMM not yet open — wait for prep
            if (t == 0) {
                while (__hip_atomic_load(p0done, __ATOMIC_ACQUIRE, AGS) < 257)
                    __builtin_amdgcn_s_sleep(8);
            }
        }
    }

    // ---------------- P2: merge (32 items), gated on all GEMM tiles complete ----------------
    WAITGE(p1done, NTILES);
    for (;;) {
        __syncthreads();
        if (t == 0) sgrab = atomicAdd(m_ctr, 1);
        __syncthreads();
        int m = sgrab;
        if (m >= 32) break;

        int j = m * 256 + t;
        bool rowside = (j < BDIM);
        int i = rowside ? j : j - BDIM;
        const float* PM  = rowside ? rPM  : cPM;
        const float* PS1 = rowside ? rPS1 : cPS1;
        const float* PS2 = rowside ? rPS2 : cPS2;
        float it = rowside ? rowIT[i] : colIT[i];

        float M = -INFINITY, S1 = 0.f, S2 = 0.f;
        for (int k = 0; k < 64; k++) {
            float mm = PM [k * BDIM + i];
            float s1 = PS1[k * BDIM + i];
            float s2 = PS2[k * BDIM + i];
            float Mn = fmaxf(M, mm);
            float ea = __expf((M - Mn) * it);
            float eb = __expf((mm - Mn) * it);
            S1 = S1 * ea + s1 * eb;
            S2 = S2 * ea + s2 * eb;
            M = Mn;
        }

        int id = ids[i];
        float tau  = rowside ? tau_I[id] : tau_T[id];
        float oldb = rowside ? b_I[id]   : b_T[id];
        float olds = rowside ? s_I[id]   : s_T[id];
        float oldu = rowside ? u_I[id]   : u_T[id];
        float dg = diag[i];

        float nb = fmaxf(oldb, (M - dg) * it);
        float F  = __expf((M - dg) * it - nb);
        float ed = __expf(-nb);
        float g  = F * S1 - ed;
        float Cs = F * (S2 - dg * S1);

        float s_new = (1.f - C_GAMMA_S) * olds * __expf(oldb - nb) + C_GAMMA_S * g;
        float scl = fmaxf(s_new, C_EPS);
        float loss = Cs / scl;
        float grad = logf(scl) + nb + C_RHO - (Cs / (scl * tau)) * (1.0f / (float)(BDIM - 1));
        float gcl = fminf(fmaxf(grad, -C_GRAD_CLIP), C_GRAD_CLIP);
        float u_new = (1.f - C_GAMMA_U) * oldu + C_GAMMA_U * gcl;
        float tau_new = fminf(fmaxf(tau - C_ETA * u_new, C_TAU_MIN), C_TAU_MAX);

        if (rowside) { O[i] = g; O[8192 + i] = grad; }
        else         { O[4096 + i] = g; O[12288 + i] = grad; }
        int base = rowside ? 0 : 4;
        sc_arrs[(base + 0) * BDIM + i] = s_new;
        sc_arrs[(base + 1) * BDIM + i] = nb;
        sc_arrs[(base + 2) * BDIM + i] = u_new;
        sc_arrs[(base + 3) * BDIM + i] = tau_new;

        sm.p0.red[t] = loss;
        __syncthreads();
        for (int s = 128; s > 0; s >>= 1) {
            if (t < s) sm.p0.red[t] += sm.p0.red[t + s];
            __syncthreads();
        }
        if (t == 0) {
            atomicAdd(&acc4[rowside ? 0 : 1], sm.p0.red[0]);
            __threadfence();
            int old = atomicAdd(ticket, 1);
            if (old == 31) {
                float li = atomicAdd(&acc4[0], 0.f);
                float lt = atomicAdd(&acc4[1], 0.f);
                float invB = 1.0f / (float)BDIM;
                O[16384] = C_ALPHA * (li * invB) + (1.f - C_ALPHA) * (lt * invB);
                O[16385] = acc4[2] * invB;
                O[16386] = acc4[3] * invB;
            }
        }
        DONE1(m_done);
    }

    // ---------------- P3 (fb only): bank-0 prefix copy after merge released the scratch ----------------
    if (fb) {
        WAITGE(m_done, 32);
        for (;;) {
            __syncthreads();
            if (t == 0) sgrab = atomicAdd(pfx_ctr, 1);
            __syncthreads();
            int c = sgrab;
            if (c >= NPFX) break;
            long f0 = (long)c * CHUNK_F;
            long fend = f0 + CHUNK_F; if (fend > PREFIX) fend = PREFIX;
            const nf4* s4 = (const nf4*)s_I;
            for (long k = f0 / 4 + t; k < fend / 4; k += 256) nt_copy4(s4, k, o);
            DONE1(pfx_done);
        }
    }

    // ---------------- P4: scatter updated state (after ALL plain copies of same addresses) ----------------
    if (t == 0) {
        while (__hip_atomic_load(c_done, __ATOMIC_ACQUIRE, AGS) < NCHUNKS) __builtin_amdgcn_s_sleep(8);
        while (__hip_atomic_load(m_done, __ATOMIC_ACQUIRE, AGS) < 32) __builtin_amdgcn_s_sleep(8);
        if (fb) {
            while (__hip_atomic_load(pfx_done, __ATOMIC_ACQUIRE, AGS) < NPFX) __builtin_amdgcn_s_sleep(8);
        }
        __threadfence();
    }
    __syncthreads();
    for (;;) {
        __syncthreads();
        if (t == 0) sgrab = atomicAdd(sc_ctr, 1);
        __syncthreads();
        int s = sgrab;
        if (s >= 16) break;
        int idx = s * 256 + t;
        long id = ids[idx];
        o[0L * NSTATE + id] = sc_arrs[0 * BDIM + idx];
        o[1L * NSTATE + id] = sc_arrs[4 * BDIM + idx];
        o[2L * NSTATE + id] = sc_arrs[1 * BDIM + idx];
        o[3L * NSTATE + id] = sc_arrs[5 * BDIM + idx];
        o[4L * NSTATE + id] = sc_arrs[2 * BDIM + idx];
        o[5L * NSTATE + id] = sc_arrs[6 * BDIM + idx];
        o[6L * NSTATE + id] = sc_arrs[3 * BDIM + idx];
        o[7L * NSTATE + id] = sc_arrs[7 * BDIM + idx];
    }
#undef WAITGE
#undef DONE1
}

extern "C" void kernel_launch(void* const* d_in, const int* in_sizes, int n_in,
                              void* d_out, int out_size, void* d_ws, size_t ws_size,
                              hipStream_t stream) {
    const float* zis   = (const float*)d_in[0];
    const float* zjs   = (const float*)d_in[1];
    const int*   ids   = (const int*)d_in[2];
    const float* s_I   = (const float*)d_in[3];
    const float* s_T   = (const float*)d_in[4];
    const float* b_I   = (const float*)d_in[5];
    const float* b_T   = (const float*)d_in[6];
    const float* u_I   = (const float*)d_in[7];
    const float* u_T   = (const float*)d_in[8];
    const float* tau_I = (const float*)d_in[9];
    const float* tau_T = (const float*)d_in[10];
    float* O  = (float*)d_out;
    float* ws = (float*)d_ws;

    // big workspace: scratch + AB fragments in ws; small: in o's bank-0 prefix (fb mode)
    const bool bigws = ws_size >= (size_t)16 * 1024 * 1024;
    float* Sb = bigws ? (ws + 53248) : (O + 16388);
    int fb = bigws ? 0 : 1;

    kinit<<<1, 64, 0, stream>>>(ws);
    kall<<<GRID, 256, 0, stream>>>(zis, zjs, ids,
                                   s_I, s_T, b_I, b_T, u_I, u_T, tau_I, tau_T,
                                   O, ws, Sb, fb);
}

// Round 3
// 548.961 us; speedup vs baseline: 2.6917x; 2.6917x over previous
//
#include <hip/hip_runtime.h>
#include <math.h>

#define BDIM 4096
#define DDIM 256
#define NSTATE 9000000
// fallback (small-ws) scheme: bank-0 prefix holding live scratch, copied late:
#define PREFIX 3674116
#define PREFIX_N4 918529     // PREFIX / 4
#define COPY_THREADS 1048576 // 4096 copy blocks * 256

#define C_ALPHA 0.5f
#define C_GAMMA_S 0.8f
#define C_GAMMA_U 0.9f
#define C_RHO 6.0f
#define C_EPS 1e-14f
#define C_ETA 0.01f
#define C_TAU_MIN 0.001f
#define C_TAU_MAX 1.0f
#define C_GRAD_CLIP 5.0f

typedef unsigned short u16;
typedef __attribute__((ext_vector_type(8))) short short8;
typedef __attribute__((ext_vector_type(16))) float f32x16;
typedef __attribute__((ext_vector_type(4))) float nf4;

#define MFMA32 __builtin_amdgcn_mfma_f32_32x32x16_bf16

__device__ inline u16 f2bf(float f) {
    unsigned u = __float_as_uint(f);
    unsigned r = (u + 0x7FFFu + ((u >> 16) & 1u)) >> 16;
    return (u16)r;
}
__device__ inline float bf2f(u16 h) { return __uint_as_float(((unsigned)h) << 16); }

__device__ inline void nt_copy4(const nf4* __restrict__ s, long k, float* __restrict__ dbase) {
    nf4 v = __builtin_nontemporal_load(&s[k]);
    float* dp = dbase + 4 * k;
    __builtin_nontemporal_store(v.x, dp + 0);
    __builtin_nontemporal_store(v.y, dp + 1);
    __builtin_nontemporal_store(v.z, dp + 2);
    __builtin_nontemporal_store(v.w, dp + 3);
}

// ---------- K1: normalize + split to bf16 hi/lo in MFMA-fragment layout ----------
// block 256: 1/tau, tau sums, and reset of loss accumulators + ticket.
__global__ __launch_bounds__(256) void kprep(const float* __restrict__ zis,
                                             const float* __restrict__ zjs,
                                             u16* __restrict__ Ah, u16* __restrict__ Al,
                                             u16* __restrict__ Bh, u16* __restrict__ Bl,
                                             const int* __restrict__ ids,
                                             const float* __restrict__ tau_I,
                                             const float* __restrict__ tau_T,
                                             float* __restrict__ rowIT,
                                             float* __restrict__ colIT,
                                             float* __restrict__ acc4,
                                             int* __restrict__ ticket) {
    int blk = blockIdx.x;                 // 0..256
    int t = threadIdx.x;
    if (blk == 256) {
        float sI = 0.f, sT = 0.f;
        for (int i = t; i < BDIM; i += 256) {
            int id = ids[i];
            float ti = tau_I[id], tt = tau_T[id];
            rowIT[i] = 1.0f / ti;
            colIT[i] = 1.0f / tt;
            sI += ti; sT += tt;
        }
        __shared__ float red[512];
        red[t] = sI; red[256 + t] = sT;
        __syncthreads();
        for (int s = 128; s > 0; s >>= 1) {
            if (t < s) { red[t] += red[t + s]; red[256 + t] += red[256 + t + s]; }
            __syncthreads();
        }
        if (t == 0) {
            acc4[0] = 0.f;        // loss_I accumulator
            acc4[1] = 0.f;        // loss_T accumulator
            acc4[2] = red[0];     // sum tau_I
            acc4[3] = red[256];   // sum tau_T
            *ticket = 0;
        }
        return;
    }
    bool isB = blk >= 128;
    const float* Z = isB ? zjs : zis;
    u16* H = isB ? Bh : Ah;
    u16* L = isB ? Bl : Al;
    int rblk = blk & 127;
    int r = t & 31, kc0 = t >> 5;         // 8 threads per row
    int row = rblk * 32 + r;

    __shared__ float ssq[32];
    if (t < 32) ssq[t] = 0.f;
    __syncthreads();

    float4 v[8];
    float partial = 0.f;
#pragma unroll
    for (int c = 0; c < 4; ++c) {
        int kc = kc0 + 8 * c;
        float4 a = *(const float4*)&Z[(size_t)row * DDIM + kc * 8];
        float4 b = *(const float4*)&Z[(size_t)row * DDIM + kc * 8 + 4];
        v[2 * c] = a; v[2 * c + 1] = b;
        partial += a.x * a.x + a.y * a.y + a.z * a.z + a.w * a.w;
        partial += b.x * b.x + b.y * b.y + b.z * b.z + b.w * b.w;
    }
    atomicAdd(&ssq[r], partial);
    __syncthreads();
    float inv = rsqrtf(ssq[r]);

#pragma unroll
    for (int c = 0; c < 4; ++c) {
        int kc = kc0 + 8 * c;
        float f[8];
        f[0] = v[2*c].x * inv;   f[1] = v[2*c].y * inv;
        f[2] = v[2*c].z * inv;   f[3] = v[2*c].w * inv;
        f[4] = v[2*c+1].x * inv; f[5] = v[2*c+1].y * inv;
        f[6] = v[2*c+1].z * inv; f[7] = v[2*c+1].w * inv;
        u16 hh[8], ll[8];
#pragma unroll
        for (int j = 0; j < 8; ++j) {
            hh[j] = f2bf(f[j]);
            ll[j] = f2bf(f[j] - bf2f(hh[j]));
        }
        size_t base = (size_t)rblk * 8192 + (size_t)kc * 256 + (size_t)r * 8;
        uint4 ph, pl;
        ph.x = (unsigned)hh[0] | ((unsigned)hh[1] << 16);
        ph.y = (unsigned)hh[2] | ((unsigned)hh[3] << 16);
        ph.z = (unsigned)hh[4] | ((unsigned)hh[5] << 16);
        ph.w = (unsigned)hh[6] | ((unsigned)hh[7] << 16);
        pl.x = (unsigned)ll[0] | ((unsigned)ll[1] << 16);
        pl.y = (unsigned)ll[2] | ((unsigned)ll[3] << 16);
        pl.z = (unsigned)ll[4] | ((unsigned)ll[5] << 16);
        pl.w = (unsigned)ll[6] | ((unsigned)ll[7] << 16);
        *(uint4*)(H + base) = ph;
        *(uint4*)(L + base) = pl;
    }
}

// ---------- K2: fused MFMA GEMM (1024 blocks) + nontemporal state copy (4096 blocks) ----------
__global__ __launch_bounds__(256, 3) void kmain(
    const u16* __restrict__ Ah, const u16* __restrict__ Al,
    const u16* __restrict__ Bh, const u16* __restrict__ Bl,
    const float* __restrict__ rowIT, const float* __restrict__ colIT,
    float* __restrict__ rPM, float* __restrict__ rPS1, float* __restrict__ rPS2,
    float* __restrict__ cPM, float* __restrict__ cPS1, float* __restrict__ cPS2,
    float* __restrict__ diag,
    const float* __restrict__ s_I, const float* __restrict__ s_T,
    const float* __restrict__ b_I, const float* __restrict__ b_T,
    const float* __restrict__ u_I, const float* __restrict__ u_T,
    const float* __restrict__ tau_I, const float* __restrict__ tau_T,
    long b0s, float* o)
{
    __shared__ float T[2][64 * 68];
    int bid = blockIdx.x;
    int t = threadIdx.x;

    if (bid % 5 != 0) {
        long cid = (long)(bid / 5) * 4 + (bid % 5) - 1;   // 0..4095
        long tid = cid * 256 + t;
        {
            const nf4* s = (const nf4*)(s_I + b0s);
            float* d = o + b0s;
            long n4 = (NSTATE - b0s) / 4;
            for (long k = tid; k < n4; k += COPY_THREADS) nt_copy4(s, k, d);
        }
        const float* srcs[7] = {s_T, b_I, b_T, u_I, u_T, tau_I, tau_T};
#pragma unroll
        for (int b = 0; b < 7; b++) {
            const nf4* s = (const nf4*)srcs[b];
            float* d = o + (long)(b + 1) * NSTATE;
            for (long k = tid; k < NSTATE / 4; k += COPY_THREADS) nt_copy4(s, k, d);
        }
        return;
    }

    int gid = bid / 5;                 // 0..1023
    int by = gid >> 5, bx = gid & 31;
    int w = t >> 6, l = t & 63;
    int rw = w & 1, cw = w >> 1;
    int h = l >> 5, lc = l & 31;
    int rowbase = by * 128 + rw * 64;
    int colbase = bx * 128 + cw * 64;

    const u16* pAh = Ah + (size_t)(by * 4 + rw * 2) * 8192;
    const u16* pAl = Al + (size_t)(by * 4 + rw * 2) * 8192;
    const u16* pBh = Bh + (size_t)(bx * 4 + cw * 2) * 8192;
    const u16* pBl = Bl + (size_t)(bx * 4 + cw * 2) * 8192;

    f32x16 acc00, acc01, acc10, acc11;
#pragma unroll
    for (int e = 0; e < 16; ++e) { acc00[e] = 0.f; acc01[e] = 0.f; acc10[e] = 0.f; acc11[e] = 0.f; }

    for (int s = 0; s < 16; ++s) {
        int off = s * 512 + l * 8;
        short8 a0h = *(const short8*)(pAh + off);
        short8 a1h = *(const short8*)(pAh + 8192 + off);
        short8 a0l = *(const short8*)(pAl + off);
        short8 a1l = *(const short8*)(pAl + 8192 + off);
        short8 b0h = *(const short8*)(pBh + off);
        short8 b1h = *(const short8*)(pBh + 8192 + off);
        short8 b0l = *(const short8*)(pBl + off);
        short8 b1l = *(const short8*)(pBl + 8192 + off);

        acc00 = MFMA32(a0h, b0h, acc00, 0, 0, 0);
        acc01 = MFMA32(a0h, b1h, acc01, 0, 0, 0);
        acc10 = MFMA32(a1h, b0h, acc10, 0, 0, 0);
        acc11 = MFMA32(a1h, b1h, acc11, 0, 0, 0);
        acc00 = MFMA32(a0h, b0l, acc00, 0, 0, 0);
        acc01 = MFMA32(a0h, b1l, acc01, 0, 0, 0);
        acc10 = MFMA32(a1h, b0l, acc10, 0, 0, 0);
        acc11 = MFMA32(a1h, b1l, acc11, 0, 0, 0);
        acc00 = MFMA32(a0l, b0h, acc00, 0, 0, 0);
        acc01 = MFMA32(a0l, b1h, acc01, 0, 0, 0);
        acc10 = MFMA32(a1l, b0h, acc10, 0, 0, 0);
        acc11 = MFMA32(a1l, b1h, acc11, 0, 0, 0);
    }

#define COLPART(A0, A1, CT) do {                                                   \
        int gc = colbase + (CT) * 32 + lc;                                         \
        float itc = colIT[gc];                                                     \
        float m = -INFINITY;                                                       \
        _Pragma("unroll") for (int e = 0; e < 16; ++e) {                           \
            m = fmaxf(m, (A0)[e]); m = fmaxf(m, (A1)[e]); }                        \
        m = fmaxf(m, __shfl_xor(m, 32));                                           \
        float S1 = 0.f, S2 = 0.f;                                                  \
        _Pragma("unroll") for (int e = 0; e < 16; ++e) {                           \
            float v0 = (A0)[e]; float e0 = __expf((v0 - m) * itc); S1 += e0; S2 += e0 * v0; \
            float v1 = (A1)[e]; float e1 = __expf((v1 - m) * itc); S1 += e1; S2 += e1 * v1; } \
        S1 += __shfl_xor(S1, 32); S2 += __shfl_xor(S2, 32);                        \
        if (h == 0) { int slot = by * 2 + rw;                                      \
            cPM [slot * 4096 + gc] = m;                                            \
            cPS1[slot * 4096 + gc] = S1;                                           \
            cPS2[slot * 4096 + gc] = S2; }                                         \
    } while (0)

    COLPART(acc00, acc10, 0);
    COLPART(acc01, acc11, 1);

#define ROWPART(TB) do {                                                           \
        float* Tb = (TB);                                                          \
        _Pragma("unroll") for (int q = 0; q < 4; ++q) {                            \
            _Pragma("unroll") for (int j = 0; j < 4; ++j) {                        \
                int rr = 8 * q + 4 * h + j;                                        \
                Tb[(rr     ) * 68 + lc     ] = acc00[4 * q + j];                   \
                Tb[(rr     ) * 68 + lc + 32] = acc01[4 * q + j];                   \
                Tb[(rr + 32) * 68 + lc     ] = acc10[4 * q + j];                   \
                Tb[(rr + 32) * 68 + lc + 32] = acc11[4 * q + j]; } }               \
        float itr = rowIT[rowbase + l];                                            \
        float4 vv[16];                                                             \
        _Pragma("unroll") for (int c = 0; c < 16; ++c)                             \
            vv[c] = *(const float4*)&Tb[l * 68 + 4 * c];                           \
        float m = -INFINITY;                                                       \
        _Pragma("unroll") for (int c = 0; c < 16; ++c)                             \
            m = fmaxf(m, fmaxf(fmaxf(vv[c].x, vv[c].y), fmaxf(vv[c].z, vv[c].w))); \
        float S1 = 0.f, S2 = 0.f;                                                  \
        _Pragma("unroll") for (int c = 0; c < 16; ++c) {                           \
            float e0 = __expf((vv[c].x - m) * itr); S1 += e0; S2 += e0 * vv[c].x;  \
            float e1 = __expf((vv[c].y - m) * itr); S1 += e1; S2 += e1 * vv[c].y;  \
            float e2 = __expf((vv[c].z - m) * itr); S1 += e2; S2 += e2 * vv[c].z;  \
            float e3 = __expf((vv[c].w - m) * itr); S1 += e3; S2 += e3 * vv[c].w; }\
        int slot = bx * 2 + cw;                                                    \
        rPM [slot * 4096 + rowbase + l] = m;                                       \
        rPS1[slot * 4096 + rowbase + l] = S1;                                      \
        rPS2[slot * 4096 + rowbase + l] = S2;                                      \
        if (bx == by && rw == cw) diag[rowbase + l] = Tb[l * 68 + l];              \
    } while (0)

    if (w < 2) ROWPART(T[w]);
    __syncthreads();
    if (w >= 2) ROWPART(T[w - 2]);
}

// ---------- K3: merge partials + state math + direct scatter (banks 1..7) + ticketed scalars ----------
// Stream order guarantees kmain's bulk copy is complete, so every bank except the
// fb bank-0 prefix can be scattered directly here. s_I's 4096 values are staged
// for kfix's tail block (bank-0 prefix is rewritten by kfix after us).
__global__ __launch_bounds__(256) void kmerge(
    const int* __restrict__ ids,
    const float* __restrict__ s_I, const float* __restrict__ b_I,
    const float* __restrict__ u_I, const float* __restrict__ tau_I,
    const float* __restrict__ s_T, const float* __restrict__ b_T,
    const float* __restrict__ u_T, const float* __restrict__ tau_T,
    const float* __restrict__ rowIT, const float* __restrict__ colIT,
    const float* __restrict__ diag,
    const float* __restrict__ rPM, const float* __restrict__ rPS1, const float* __restrict__ rPS2,
    const float* __restrict__ cPM, const float* __restrict__ cPS1, const float* __restrict__ cPS2,
    float* __restrict__ O,
    float* __restrict__ sc_arrs,     // staging for fb bank-0 (s_I) scatter values
    float* o_dir,                    // direct-scatter target (always o)
    int fbmode,                      // 1: stage s_I values; 0 (bigws): scatter all 8 banks
    float* acc4, int* ticket)
{
    int j = blockIdx.x * 256 + threadIdx.x;
    int t = threadIdx.x;
    bool rowside = (j < BDIM);
    int i = rowside ? j : j - BDIM;
    const float* PM  = rowside ? rPM  : cPM;
    const float* PS1 = rowside ? rPS1 : cPS1;
    const float* PS2 = rowside ? rPS2 : cPS2;
    float it = rowside ? rowIT[i] : colIT[i];

    float M = -INFINITY, S1 = 0.f, S2 = 0.f;
    for (int k = 0; k < 64; k++) {
        float m  = PM [k * BDIM + i];
        float s1 = PS1[k * BDIM + i];
        float s2 = PS2[k * BDIM + i];
        float Mn = fmaxf(M, m);
        float ea = __expf((M - Mn) * it);
        float eb = __expf((m - Mn) * it);
        S1 = S1 * ea + s1 * eb;
        S2 = S2 * ea + s2 * eb;
        M = Mn;
    }

    int id = ids[i];
    float tau  = rowside ? tau_I[id] : tau_T[id];
    float oldb = rowside ? b_I[id]   : b_T[id];
    float olds = rowside ? s_I[id]   : s_T[id];
    float oldu = rowside ? u_I[id]   : u_T[id];
    float dg = diag[i];

    float nb = fmaxf(oldb, (M - dg) * it);
    float F  = __expf((M - dg) * it - nb);
    float ed = __expf(-nb);
    float g  = F * S1 - ed;
    float Cs = F * (S2 - dg * S1);

    float s_new = (1.f - C_GAMMA_S) * olds * __expf(oldb - nb) + C_GAMMA_S * g;
    float scl = fmaxf(s_new, C_EPS);
    float loss = Cs / scl;
    float grad = logf(scl) + nb + C_RHO - (Cs / (scl * tau)) * (1.0f / (float)(BDIM - 1));
    float gc = fminf(fmaxf(grad, -C_GRAD_CLIP), C_GRAD_CLIP);
    float u_new = (1.f - C_GAMMA_U) * oldu + C_GAMMA_U * gc;
    float tau_new = fminf(fmaxf(tau - C_ETA * u_new, C_TAU_MIN), C_TAU_MAX);

    int bank0 = rowside ? 0 : 1;   // s, then b(+2), u(+4), tau(+6)
    if (rowside) {
        O[i] = g;
        O[8192 + i] = grad;
    } else {
        O[4096 + i] = g;
        O[12288 + i] = grad;
    }
    long lid = id;
    // direct scatters — addresses written by kmain's (earlier, completed) bulk copy
    o_dir[(long)(bank0 + 2) * NSTATE + lid] = nb;
    o_dir[(long)(bank0 + 4) * NSTATE + lid] = u_new;
    o_dir[(long)(bank0 + 6) * NSTATE + lid] = tau_new;
    if (rowside) {
        if (fbmode) sc_arrs[i] = s_new;                 // bank-0 prefix rewritten by kfix later
        else        o_dir[lid] = s_new;
    } else {
        o_dir[(long)1 * NSTATE + lid] = s_new;          // s_T: safe in both modes
    }

    // block loss reduction -> one atomic per block (rowside uniform per block)
    __shared__ float red[256];
    red[t] = loss;
    __syncthreads();
    for (int s = 128; s > 0; s >>= 1) {
        if (t < s) red[t] += red[t + s];
        __syncthreads();
    }
    if (t == 0) {
        atomicAdd(&acc4[rowside ? 0 : 1], red[0]);
        __threadfence();
        int old = atomicAdd(ticket, 1);
        if (old == 31) {
            float li = atomicAdd(&acc4[0], 0.f);
            float lt = atomicAdd(&acc4[1], 0.f);
            float invB = 1.0f / (float)BDIM;
            O[16384] = C_ALPHA * (li * invB) + (1.f - C_ALPHA) * (lt * invB);
            O[16385] = acc4[2] * invB;
            O[16386] = acc4[3] * invB;
        }
    }
}

// ---------- K4b (fallback): prefix copy + fused s_I scatter ----------
// Blocks 0..3583: copy o[4096, PREFIX). Block 3584: copy o[0, 4096) then scatter
// s_new at ids (intra-block __syncthreads ordering; ids < 4096 land in this
// block's exclusive region; ids >= PREFIX are untouched by any other block).
__global__ __launch_bounds__(256) void kfix(const float* __restrict__ s_I,
                                            const int* __restrict__ ids,
                                            const float* __restrict__ sc_arrs,
                                            float* __restrict__ o) {
    int t = threadIdx.x;
    if (blockIdx.x == 3584) {
        const nf4* s = (const nf4*)s_I;
        for (long k = t; k < 1024; k += 256) nt_copy4(s, k, o);   // o[0..4096)
        __syncthreads();
#pragma unroll
        for (int j = 0; j < 16; ++j) {
            int idx = t * 16 + j;
            long id = ids[idx];
            o[id] = sc_arrs[idx];
        }
        return;
    }
    long tid = (long)blockIdx.x * 256 + t;
    const nf4* s = (const nf4*)s_I;
    for (long k = 1024 + tid; k < PREFIX_N4; k += 3584L * 256) nt_copy4(s, k, o);
}

extern "C" void kernel_launch(void* const* d_in, const int* in_sizes, int n_in,
                              void* d_out, int out_size, void* d_ws, size_t ws_size,
                              hipStream_t stream) {
    const float* zis   = (const float*)d_in[0];
    const float* zjs   = (const float*)d_in[1];
    const int*   ids   = (const int*)d_in[2];
    const float* s_I   = (const float*)d_in[3];
    const float* s_T   = (const float*)d_in[4];
    const float* b_I   = (const float*)d_in[5];
    const float* b_T   = (const float*)d_in[6];
    const float* u_I   = (const float*)d_in[7];
    const float* u_T   = (const float*)d_in[8];
    const float* tau_I = (const float*)d_in[9];
    const float* tau_T = (const float*)d_in[10];
    float* O  = (float*)d_out;
    float* ws = (float*)d_ws;

    // small arrays always in ws
    float* rowIT  = ws;                         // 4096 each
    float* colIT  = ws + 4096;
    float* acc4   = ws + 8192;                  // lossI, lossT, tauIsum, tauTsum
    int*   ticket = (int*)(ws + 8196);
    float* sc_arrs = ws + 16384;                // 4096 staged s_I scatter values (fb)

    const bool bigws = ws_size >= (size_t)16 * 1024 * 1024;

    float *rPM, *rPS1, *rPS2, *cPM, *cPS1, *cPS2, *diag;
    u16 *Ah, *Al, *Bh, *Bl;
    long b0s;
    if (bigws) {
        float* P = ws + 53248;                  // big scratch in d_ws
        rPM  = P;            rPS1 = P + 262144;  rPS2 = P + 524288;
        cPM  = P + 786432;   cPS1 = P + 1048576; cPS2 = P + 1310720;
        diag = P + 1572864;
        Ah = (u16*)(P + 1576960);
        Al = Ah + 1048576; Bh = Al + 1048576; Bl = Bh + 1048576;
        b0s = 0;
    } else {
        float* P = O + 16388;                   // fallback: d_out bank-0 prefix
        rPM  = P;            rPS1 = P + 262144;  rPS2 = P + 524288;
        cPM  = P + 786432;   cPS1 = P + 1048576; cPS2 = P + 1310720;
        diag = P + 1572864;
        Ah = (u16*)(P + 1576960);
        Al = Ah + 1048576; Bh = Al + 1048576; Bl = Bh + 1048576;
        b0s = PREFIX;
    }

    kprep<<<257, 256, 0, stream>>>(zis, zjs, Ah, Al, Bh, Bl,
                                   ids, tau_I, tau_T, rowIT, colIT, acc4, ticket);

    kmain<<<5120, 256, 0, stream>>>(Ah, Al, Bh, Bl, rowIT, colIT,
                                    rPM, rPS1, rPS2, cPM, cPS1, cPS2, diag,
                                    s_I, s_T, b_I, b_T, u_I, u_T, tau_I, tau_T,
                                    b0s, O + 16387);

    kmerge<<<32, 256, 0, stream>>>(ids, s_I, b_I, u_I, tau_I, s_T, b_T, u_T, tau_T,
                                   rowIT, colIT, diag,
                                   rPM, rPS1, rPS2, cPM, cPS1, cPS2,
                                   O, sc_arrs, O + 16387, bigws ? 0 : 1,
                                   acc4, ticket);

    if (!bigws) {
        kfix<<<3585, 256, 0, stream>>>(s_I, ids, sc_arrs, O + 16387);
    }
}

// Round 4
// 543.945 us; speedup vs baseline: 2.7166x; 1.0092x over previous
//
#include <hip/hip_runtime.h>
#include <math.h>

#define BDIM 4096
#define DDIM 256
#define NSTATE 9000000
// fallback (small-ws) scheme: bank-0 prefix holding live scratch, copied late:
#define PREFIX 3674116
#define COPY_THREADS 1048576 // 4096 copy blocks * 256

#define C_ALPHA 0.5f
#define C_GAMMA_S 0.8f
#define C_GAMMA_U 0.9f
#define C_RHO 6.0f
#define C_EPS 1e-14f
#define C_ETA 0.01f
#define C_TAU_MIN 0.001f
#define C_TAU_MAX 1.0f
#define C_GRAD_CLIP 5.0f

typedef unsigned short u16;
typedef __attribute__((ext_vector_type(8))) short short8;
typedef __attribute__((ext_vector_type(16))) float f32x16;
typedef __attribute__((ext_vector_type(4))) float nf4;

#define MFMA32 __builtin_amdgcn_mfma_f32_32x32x16_bf16

__device__ inline u16 f2bf(float f) {
    unsigned u = __float_as_uint(f);
    unsigned r = (u + 0x7FFFu + ((u >> 16) & 1u)) >> 16;
    return (u16)r;
}
__device__ inline float bf2f(u16 h) { return __uint_as_float(((unsigned)h) << 16); }

// Copy S[a..n) -> D[a..n) where D+a is byte ≡ 12 (mod 16): the vector frame is
// shifted by +1 float so every 16B store is ALIGNED and DENSE across the wave
// (full-line write-combining). Loads go scalar (partial-line reads are free:
// lines are fetched whole and sibling instructions hit L1).
__device__ inline void copy_span(const float* __restrict__ S, float* __restrict__ D,
                                 long a, long n, long tid, long nthreads) {
    long m0 = a + 1;              // first vector element (D+m0 is 16B-aligned)
    long M = (n - m0) >> 2;       // number of float4 groups
    for (long m = tid; m < M; m += nthreads) {
        long i = m0 + 4 * m;
        nf4 v;
        v.x = __builtin_nontemporal_load(S + i);
        v.y = __builtin_nontemporal_load(S + i + 1);
        v.z = __builtin_nontemporal_load(S + i + 2);
        v.w = __builtin_nontemporal_load(S + i + 3);
        __builtin_nontemporal_store(v, (nf4*)(D + i));
    }
    if (tid == 0) D[a] = S[a];                                  // head
    long tail = n - m0 - 4 * M;                                 // 0..3
    if (tid >= 1 && tid <= tail) { long i = n - tid; D[i] = S[i]; }
}

// ---------- K1: normalize + split to bf16 hi/lo in MFMA-fragment layout ----------
// block 256: 1/tau, tau sums, and reset of loss accumulators + ticket.
__global__ __launch_bounds__(256) void kprep(const float* __restrict__ zis,
                                             const float* __restrict__ zjs,
                                             u16* __restrict__ Ah, u16* __restrict__ Al,
                                             u16* __restrict__ Bh, u16* __restrict__ Bl,
                                             const int* __restrict__ ids,
                                             const float* __restrict__ tau_I,
                                             const float* __restrict__ tau_T,
                                             float* __restrict__ rowIT,
                                             float* __restrict__ colIT,
                                             float* __restrict__ acc4,
                                             int* __restrict__ ticket) {
    int blk = blockIdx.x;                 // 0..256
    int t = threadIdx.x;
    if (blk == 256) {
        float sI = 0.f, sT = 0.f;
        for (int i = t; i < BDIM; i += 256) {
            int id = ids[i];
            float ti = tau_I[id], tt = tau_T[id];
            rowIT[i] = 1.0f / ti;
            colIT[i] = 1.0f / tt;
            sI += ti; sT += tt;
        }
        __shared__ float red[512];
        red[t] = sI; red[256 + t] = sT;
        __syncthreads();
        for (int s = 128; s > 0; s >>= 1) {
            if (t < s) { red[t] += red[t + s]; red[256 + t] += red[256 + t + s]; }
            __syncthreads();
        }
        if (t == 0) {
            acc4[0] = 0.f;        // loss_I accumulator
            acc4[1] = 0.f;        // loss_T accumulator
            acc4[2] = red[0];     // sum tau_I
            acc4[3] = red[256];   // sum tau_T
            *ticket = 0;
        }
        return;
    }
    bool isB = blk >= 128;
    const float* Z = isB ? zjs : zis;
    u16* H = isB ? Bh : Ah;
    u16* L = isB ? Bl : Al;
    int rblk = blk & 127;
    int r = t & 31, kc0 = t >> 5;         // 8 threads per row
    int row = rblk * 32 + r;

    __shared__ float ssq[32];
    if (t < 32) ssq[t] = 0.f;
    __syncthreads();

    float4 v[8];
    float partial = 0.f;
#pragma unroll
    for (int c = 0; c < 4; ++c) {
        int kc = kc0 + 8 * c;
        float4 a = *(const float4*)&Z[(size_t)row * DDIM + kc * 8];
        float4 b = *(const float4*)&Z[(size_t)row * DDIM + kc * 8 + 4];
        v[2 * c] = a; v[2 * c + 1] = b;
        partial += a.x * a.x + a.y * a.y + a.z * a.z + a.w * a.w;
        partial += b.x * b.x + b.y * b.y + b.z * b.z + b.w * b.w;
    }
    atomicAdd(&ssq[r], partial);
    __syncthreads();
    float inv = rsqrtf(ssq[r]);

#pragma unroll
    for (int c = 0; c < 4; ++c) {
        int kc = kc0 + 8 * c;
        float f[8];
        f[0] = v[2*c].x * inv;   f[1] = v[2*c].y * inv;
        f[2] = v[2*c].z * inv;   f[3] = v[2*c].w * inv;
        f[4] = v[2*c+1].x * inv; f[5] = v[2*c+1].y * inv;
        f[6] = v[2*c+1].z * inv; f[7] = v[2*c+1].w * inv;
        u16 hh[8], ll[8];
#pragma unroll
        for (int j = 0; j < 8; ++j) {
            hh[j] = f2bf(f[j]);
            ll[j] = f2bf(f[j] - bf2f(hh[j]));
        }
        size_t base = (size_t)rblk * 8192 + (size_t)kc * 256 + (size_t)r * 8;
        uint4 ph, pl;
        ph.x = (unsigned)hh[0] | ((unsigned)hh[1] << 16);
        ph.y = (unsigned)hh[2] | ((unsigned)hh[3] << 16);
        ph.z = (unsigned)hh[4] | ((unsigned)hh[5] << 16);
        ph.w = (unsigned)hh[6] | ((unsigned)hh[7] << 16);
        pl.x = (unsigned)ll[0] | ((unsigned)ll[1] << 16);
        pl.y = (unsigned)ll[2] | ((unsigned)ll[3] << 16);
        pl.z = (unsigned)ll[4] | ((unsigned)ll[5] << 16);
        pl.w = (unsigned)ll[6] | ((unsigned)ll[7] << 16);
        *(uint4*)(H + base) = ph;
        *(uint4*)(L + base) = pl;
    }
}

// ---------- K2: fused MFMA GEMM (1024 blocks) + nontemporal state copy (4096 blocks) ----------
__global__ __launch_bounds__(256, 3) void kmain(
    const u16* __restrict__ Ah, const u16* __restrict__ Al,
    const u16* __restrict__ Bh, const u16* __restrict__ Bl,
    const float* __restrict__ rowIT, const float* __restrict__ colIT,
    float* __restrict__ rPM, float* __restrict__ rPS1, float* __restrict__ rPS2,
    float* __restrict__ cPM, float* __restrict__ cPS1, float* __restrict__ cPS2,
    float* __restrict__ diag,
    const float* __restrict__ s_I, const float* __restrict__ s_T,
    const float* __restrict__ b_I, const float* __restrict__ b_T,
    const float* __restrict__ u_I, const float* __restrict__ u_T,
    const float* __restrict__ tau_I, const float* __restrict__ tau_T,
    long b0s, float* o)
{
    __shared__ float T[2][64 * 68];
    int bid = blockIdx.x;
    int t = threadIdx.x;

    if (bid % 5 != 0) {
        long cid = (long)(bid / 5) * 4 + (bid % 5) - 1;   // 0..4095
        long tid = cid * 256 + t;
        copy_span(s_I, o, b0s, NSTATE, tid, COPY_THREADS);
        const float* srcs[7] = {s_T, b_I, b_T, u_I, u_T, tau_I, tau_T};
#pragma unroll
        for (int b = 0; b < 7; b++)
            copy_span(srcs[b], o + (long)(b + 1) * NSTATE, 0, NSTATE, tid, COPY_THREADS);
        return;
    }

    int gid = bid / 5;                 // 0..1023
    int by = gid >> 5, bx = gid & 31;
    int w = t >> 6, l = t & 63;
    int rw = w & 1, cw = w >> 1;
    int h = l >> 5, lc = l & 31;
    int rowbase = by * 128 + rw * 64;
    int colbase = bx * 128 + cw * 64;

    const u16* pAh = Ah + (size_t)(by * 4 + rw * 2) * 8192;
    const u16* pAl = Al + (size_t)(by * 4 + rw * 2) * 8192;
    const u16* pBh = Bh + (size_t)(bx * 4 + cw * 2) * 8192;
    const u16* pBl = Bl + (size_t)(bx * 4 + cw * 2) * 8192;

    f32x16 acc00, acc01, acc10, acc11;
#pragma unroll
    for (int e = 0; e < 16; ++e) { acc00[e] = 0.f; acc01[e] = 0.f; acc10[e] = 0.f; acc11[e] = 0.f; }

    for (int s = 0; s < 16; ++s) {
        int off = s * 512 + l * 8;
        short8 a0h = *(const short8*)(pAh + off);
        short8 a1h = *(const short8*)(pAh + 8192 + off);
        short8 a0l = *(const short8*)(pAl + off);
        short8 a1l = *(const short8*)(pAl + 8192 + off);
        short8 b0h = *(const short8*)(pBh + off);
        short8 b1h = *(const short8*)(pBh + 8192 + off);
        short8 b0l = *(const short8*)(pBl + off);
        short8 b1l = *(const short8*)(pBl + 8192 + off);

        acc00 = MFMA32(a0h, b0h, acc00, 0, 0, 0);
        acc01 = MFMA32(a0h, b1h, acc01, 0, 0, 0);
        acc10 = MFMA32(a1h, b0h, acc10, 0, 0, 0);
        acc11 = MFMA32(a1h, b1h, acc11, 0, 0, 0);
        acc00 = MFMA32(a0h, b0l, acc00, 0, 0, 0);
        acc01 = MFMA32(a0h, b1l, acc01, 0, 0, 0);
        acc10 = MFMA32(a1h, b0l, acc10, 0, 0, 0);
        acc11 = MFMA32(a1h, b1l, acc11, 0, 0, 0);
        acc00 = MFMA32(a0l, b0h, acc00, 0, 0, 0);
        acc01 = MFMA32(a0l, b1h, acc01, 0, 0, 0);
        acc10 = MFMA32(a1l, b0h, acc10, 0, 0, 0);
        acc11 = MFMA32(a1l, b1h, acc11, 0, 0, 0);
    }

#define COLPART(A0, A1, CT) do {                                                   \
        int gc = colbase + (CT) * 32 + lc;                                         \
        float itc = colIT[gc];                                                     \
        float m = -INFINITY;                                                       \
        _Pragma("unroll") for (int e = 0; e < 16; ++e) {                           \
            m = fmaxf(m, (A0)[e]); m = fmaxf(m, (A1)[e]); }                        \
        m = fmaxf(m, __shfl_xor(m, 32));                                           \
        float S1 = 0.f, S2 = 0.f;                                                  \
        _Pragma("unroll") for (int e = 0; e < 16; ++e) {                           \
            float v0 = (A0)[e]; float e0 = __expf((v0 - m) * itc); S1 += e0; S2 += e0 * v0; \
            float v1 = (A1)[e]; float e1 = __expf((v1 - m) * itc); S1 += e1; S2 += e1 * v1; } \
        S1 += __shfl_xor(S1, 32); S2 += __shfl_xor(S2, 32);                        \
        if (h == 0) { int slot = by * 2 + rw;                                      \
            cPM [slot * 4096 + gc] = m;                                            \
            cPS1[slot * 4096 + gc] = S1;                                           \
            cPS2[slot * 4096 + gc] = S2; }                                         \
    } while (0)

    COLPART(acc00, acc10, 0);
    COLPART(acc01, acc11, 1);

#define ROWPART(TB) do {                                                           \
        float* Tb = (TB);                                                          \
        _Pragma("unroll") for (int q = 0; q < 4; ++q) {                            \
            _Pragma("unroll") for (int j = 0; j < 4; ++j) {                        \
                int rr = 8 * q + 4 * h + j;                                        \
                Tb[(rr     ) * 68 + lc     ] = acc00[4 * q + j];                   \
                Tb[(rr     ) * 68 + lc + 32] = acc01[4 * q + j];                   \
                Tb[(rr + 32) * 68 + lc     ] = acc10[4 * q + j];                   \
                Tb[(rr + 32) * 68 + lc + 32] = acc11[4 * q + j]; } }               \
        float itr = rowIT[rowbase + l];                                            \
        float4 vv[16];                                                             \
        _Pragma("unroll") for (int c = 0; c < 16; ++c)                             \
            vv[c] = *(const float4*)&Tb[l * 68 + 4 * c];                           \
        float m = -INFINITY;                                                       \
        _Pragma("unroll") for (int c = 0; c < 16; ++c)                             \
            m = fmaxf(m, fmaxf(fmaxf(vv[c].x, vv[c].y), fmaxf(vv[c].z, vv[c].w))); \
        float S1 = 0.f, S2 = 0.f;                                                  \
        _Pragma("unroll") for (int c = 0; c < 16; ++c) {                           \
            float e0 = __expf((vv[c].x - m) * itr); S1 += e0; S2 += e0 * vv[c].x;  \
            float e1 = __expf((vv[c].y - m) * itr); S1 += e1; S2 += e1 * vv[c].y;  \
            float e2 = __expf((vv[c].z - m) * itr); S1 += e2; S2 += e2 * vv[c].z;  \
            float e3 = __expf((vv[c].w - m) * itr); S1 += e3; S2 += e3 * vv[c].w; }\
        int slot = bx * 2 + cw;                                                    \
        rPM [slot * 4096 + rowbase + l] = m;                                       \
        rPS1[slot * 4096 + rowbase + l] = S1;                                      \
        rPS2[slot * 4096 + rowbase + l] = S2;                                      \
        if (bx == by && rw == cw) diag[rowbase + l] = Tb[l * 68 + l];              \
    } while (0)

    if (w < 2) ROWPART(T[w]);
    __syncthreads();
    if (w >= 2) ROWPART(T[w - 2]);
}

// ---------- K3: merge partials + state math + direct scatter (banks 1..7) + ticketed scalars ----------
// Stream order guarantees kmain's bulk copy is complete, so every bank except the
// fb bank-0 prefix can be scattered directly here. s_I's 4096 values are staged
// for kfix's tail block (bank-0 prefix is rewritten by kfix after us).
__global__ __launch_bounds__(256) void kmerge(
    const int* __restrict__ ids,
    const float* __restrict__ s_I, const float* __restrict__ b_I,
    const float* __restrict__ u_I, const float* __restrict__ tau_I,
    const float* __restrict__ s_T, const float* __restrict__ b_T,
    const float* __restrict__ u_T, const float* __restrict__ tau_T,
    const float* __restrict__ rowIT, const float* __restrict__ colIT,
    const float* __restrict__ diag,
    const float* __restrict__ rPM, const float* __restrict__ rPS1, const float* __restrict__ rPS2,
    const float* __restrict__ cPM, const float* __restrict__ cPS1, const float* __restrict__ cPS2,
    float* __restrict__ O,
    float* __restrict__ sc_arrs,     // staging for fb bank-0 (s_I) scatter values
    float* o_dir,                    // direct-scatter target (always o)
    int fbmode,                      // 1: stage s_I values; 0 (bigws): scatter all 8 banks
    float* acc4, int* ticket)
{
    int j = blockIdx.x * 256 + threadIdx.x;
    int t = threadIdx.x;
    bool rowside = (j < BDIM);
    int i = rowside ? j : j - BDIM;
    const float* PM  = rowside ? rPM  : cPM;
    const float* PS1 = rowside ? rPS1 : cPS1;
    const float* PS2 = rowside ? rPS2 : cPS2;
    float it = rowside ? rowIT[i] : colIT[i];

    float M = -INFINITY, S1 = 0.f, S2 = 0.f;
#pragma unroll 8
    for (int k = 0; k < 64; k++) {
        float m  = PM [k * BDIM + i];
        float s1 = PS1[k * BDIM + i];
        float s2 = PS2[k * BDIM + i];
        float Mn = fmaxf(M, m);
        float ea = __expf((M - Mn) * it);
        float eb = __expf((m - Mn) * it);
        S1 = S1 * ea + s1 * eb;
        S2 = S2 * ea + s2 * eb;
        M = Mn;
    }

    int id = ids[i];
    float tau  = rowside ? tau_I[id] : tau_T[id];
    float oldb = rowside ? b_I[id]   : b_T[id];
    float olds = rowside ? s_I[id]   : s_T[id];
    float oldu = rowside ? u_I[id]   : u_T[id];
    float dg = diag[i];

    float nb = fmaxf(oldb, (M - dg) * it);
    float F  = __expf((M - dg) * it - nb);
    float ed = __expf(-nb);
    float g  = F * S1 - ed;
    float Cs = F * (S2 - dg * S1);

    float s_new = (1.f - C_GAMMA_S) * olds * __expf(oldb - nb) + C_GAMMA_S * g;
    float scl = fmaxf(s_new, C_EPS);
    float loss = Cs / scl;
    float grad = logf(scl) + nb + C_RHO - (Cs / (scl * tau)) * (1.0f / (float)(BDIM - 1));
    float gc = fminf(fmaxf(grad, -C_GRAD_CLIP), C_GRAD_CLIP);
    float u_new = (1.f - C_GAMMA_U) * oldu + C_GAMMA_U * gc;
    float tau_new = fminf(fmaxf(tau - C_ETA * u_new, C_TAU_MIN), C_TAU_MAX);

    int bank0 = rowside ? 0 : 1;   // s, then b(+2), u(+4), tau(+6)
    if (rowside) {
        O[i] = g;
        O[8192 + i] = grad;
    } else {
        O[4096 + i] = g;
        O[12288 + i] = grad;
    }
    long lid = id;
    // direct scatters — addresses written by kmain's (earlier, completed) bulk copy
    o_dir[(long)(bank0 + 2) * NSTATE + lid] = nb;
    o_dir[(long)(bank0 + 4) * NSTATE + lid] = u_new;
    o_dir[(long)(bank0 + 6) * NSTATE + lid] = tau_new;
    if (rowside) {
        if (fbmode) sc_arrs[i] = s_new;                 // bank-0 prefix rewritten by kfix later
        else        o_dir[lid] = s_new;
    } else {
        o_dir[(long)1 * NSTATE + lid] = s_new;          // s_T: safe in both modes
    }

    // block loss reduction -> one atomic per block (rowside uniform per block)
    __shared__ float red[256];
    red[t] = loss;
    __syncthreads();
    for (int s = 128; s > 0; s >>= 1) {
        if (t < s) red[t] += red[t + s];
        __syncthreads();
    }
    if (t == 0) {
        atomicAdd(&acc4[rowside ? 0 : 1], red[0]);
        __threadfence();
        int old = atomicAdd(ticket, 1);
        if (old == 31) {
            float li = atomicAdd(&acc4[0], 0.f);
            float lt = atomicAdd(&acc4[1], 0.f);
            float invB = 1.0f / (float)BDIM;
            O[16384] = C_ALPHA * (li * invB) + (1.f - C_ALPHA) * (lt * invB);
            O[16385] = acc4[2] * invB;
            O[16386] = acc4[3] * invB;
        }
    }
}

// ---------- K4b (fallback): prefix copy + fused s_I scatter ----------
// Blocks 0..3583: copy o[4096, PREFIX). Block 3584: copy o[0, 4096) then scatter
// s_new at ids (intra-block __syncthreads ordering; ids < 4096 land in this
// block's exclusive region; ids >= PREFIX are untouched by any other block).
__global__ __launch_bounds__(256) void kfix(const float* __restrict__ s_I,
                                            const int* __restrict__ ids,
                                            const float* __restrict__ sc_arrs,
                                            float* __restrict__ o) {
    int t = threadIdx.x;
    if (blockIdx.x == 3584) {
        copy_span(s_I, o, 0, 4096, t, 256);   // o[0..4096)
        __syncthreads();
#pragma unroll
        for (int j = 0; j < 16; ++j) {
            int idx = t * 16 + j;
            long id = ids[idx];
            o[id] = sc_arrs[idx];
        }
        return;
    }
    long tid = (long)blockIdx.x * 256 + t;
    copy_span(s_I, o, 4096, PREFIX, tid, 3584L * 256);
}

extern "C" void kernel_launch(void* const* d_in, const int* in_sizes, int n_in,
                              void* d_out, int out_size, void* d_ws, size_t ws_size,
                              hipStream_t stream) {
    const float* zis   = (const float*)d_in[0];
    const float* zjs   = (const float*)d_in[1];
    const int*   ids   = (const int*)d_in[2];
    const float* s_I   = (const float*)d_in[3];
    const float* s_T   = (const float*)d_in[4];
    const float* b_I   = (const float*)d_in[5];
    const float* b_T   = (const float*)d_in[6];
    const float* u_I   = (const float*)d_in[7];
    const float* u_T   = (const float*)d_in[8];
    const float* tau_I = (const float*)d_in[9];
    const float* tau_T = (const float*)d_in[10];
    float* O  = (float*)d_out;
    float* ws = (float*)d_ws;

    // small arrays always in ws
    float* rowIT  = ws;                         // 4096 each
    float* colIT  = ws + 4096;
    float* acc4   = ws + 8192;                  // lossI, lossT, tauIsum, tauTsum
    int*   ticket = (int*)(ws + 8196);
    float* sc_arrs = ws + 16384;                // 4096 staged s_I scatter values (fb)

    const bool bigws = ws_size >= (size_t)16 * 1024 * 1024;

    float *rPM, *rPS1, *rPS2, *cPM, *cPS1, *cPS2, *diag;
    u16 *Ah, *Al, *Bh, *Bl;
    long b0s;
    if (bigws) {
        float* P = ws + 53248;                  // big scratch in d_ws
        rPM  = P;            rPS1 = P + 262144;  rPS2 = P + 524288;
        cPM  = P + 786432;   cPS1 = P + 1048576; cPS2 = P + 1310720;
        diag = P + 1572864;
        Ah = (u16*)(P + 1576960);
        Al = Ah + 1048576; Bh = Al + 1048576; Bl = Bh + 1048576;
        b0s = 0;
    } else {
        float* P = O + 16388;                   // fallback: d_out bank-0 prefix
        rPM  = P;            rPS1 = P + 262144;  rPS2 = P + 524288;
        cPM  = P + 786432;   cPS1 = P + 1048576; cPS2 = P + 1310720;
        diag = P + 1572864;
        Ah = (u16*)(P + 1576960);
        Al = Ah + 1048576; Bh = Al + 1048576; Bl = Bh + 1048576;
        b0s = PREFIX;
    }

    kprep<<<257, 256, 0, stream>>>(zis, zjs, Ah, Al, Bh, Bl,
                                   ids, tau_I, tau_T, rowIT, colIT, acc4, ticket);

    kmain<<<5120, 256, 0, stream>>>(Ah, Al, Bh, Bl, rowIT, colIT,
                                    rPM, rPS1, rPS2, cPM, cPS1, cPS2, diag,
                                    s_I, s_T, b_I, b_T, u_I, u_T, tau_I, tau_T,
                                    b0s, O + 16387);

    kmerge<<<32, 256, 0, stream>>>(ids, s_I, b_I, u_I, tau_I, s_T, b_T, u_T, tau_T,
                                   rowIT, colIT, diag,
                                   rPM, rPS1, rPS2, cPM, cPS1, cPS2,
                                   O, sc_arrs, O + 16387, bigws ? 0 : 1,
                                   acc4, ticket);

    if (!bigws) {
        kfix<<<3585, 256, 0, stream>>>(s_I, ids, sc_arrs, O + 16387);
    }
}